// Round 1
// baseline (459.041 us; speedup 1.0000x reference)
//
#include <hip/hip_runtime.h>
#include <hip/hip_bf16.h>

// Scatter-sum: out[node] += H[edge] for each edge with X_node[edge] == node.
// H: [NUM_EDGES=2e6, D=32] f32, X_node: [2e6] int (int32 per harness), out: [100000, 32] f32.
// Thread t handles (edge = t>>5, col = t&31): coalesced H reads, fp32 atomicAdd into out.

__global__ void AggrSum_46299747451335_kernel(const float* __restrict__ H,
                                              const int* __restrict__ X_node,
                                              float* __restrict__ out,
                                              int num_edges) {
    long long t = (long long)blockIdx.x * blockDim.x + threadIdx.x;
    long long total = (long long)num_edges * 32;
    if (t >= total) return;
    int edge = (int)(t >> 5);
    int col  = (int)(t & 31);
    int node = X_node[edge];           // 32 lanes broadcast-read same word; L1-served
    float v = H[t];
    atomicAdd(&out[(long long)node * 32 + col], v);
}

extern "C" void kernel_launch(void* const* d_in, const int* in_sizes, int n_in,
                              void* d_out, int out_size, void* d_ws, size_t ws_size,
                              hipStream_t stream) {
    const float* H      = (const float*)d_in[0];
    const int*   X_node = (const int*)d_in[1];
    float*       out    = (float*)d_out;

    const int num_edges = in_sizes[0] / 32;   // H is [num_edges, 32]

    // d_out is re-poisoned to 0xAA before every timed launch — zero it here.
    hipMemsetAsync(d_out, 0, (size_t)out_size * sizeof(float), stream);

    long long total_threads = (long long)num_edges * 32;
    int block = 256;
    long long grid = (total_threads + block - 1) / block;
    AggrSum_46299747451335_kernel<<<(dim3)(unsigned)grid, block, 0, stream>>>(
        H, X_node, out, num_edges);
}